// Round 1
// baseline (154.936 us; speedup 1.0000x reference)
//
#include <hip/hip_runtime.h>
#include <hip/hip_bf16.h>

#define NN 8192
#define FF 128

typedef __attribute__((ext_vector_type(8))) short bf16x8;   // 8 bf16 (4 VGPR) MFMA frag
typedef __attribute__((ext_vector_type(4))) short s16x4;
typedef __attribute__((ext_vector_type(4))) float f32x4;

__device__ __forceinline__ short f2bf(float f) {
  // round-to-nearest-even f32 -> bf16 (inputs are finite; no NaN handling needed)
  unsigned u = __float_as_uint(f);
  u += 0x7FFFu + ((u >> 16) & 1u);
  return (short)(u >> 16);
}
__device__ __forceinline__ float bf2f(short s) {
  return __uint_as_float(((unsigned)(unsigned short)s) << 16);
}

// ---- kernel 1: deg[i] = rowsum(adj)+1 ; dinv[i] = (deg+1e-8)^-0.5 ----
__global__ __launch_bounds__(256) void k_deg(const float* __restrict__ adj,
                                             float* __restrict__ dinv) {
  const int row = blockIdx.x;
  const float4* p = (const float4*)(adj + (size_t)row * NN);
  float s = 0.f;
#pragma unroll
  for (int it = 0; it < 8; ++it) {
    float4 v = p[it * 256 + threadIdx.x];
    s += (v.x + v.y) + (v.z + v.w);
  }
#pragma unroll
  for (int off = 32; off > 0; off >>= 1) s += __shfl_down(s, off, 64);
  __shared__ float partial[4];
  if ((threadIdx.x & 63) == 0) partial[threadIdx.x >> 6] = s;
  __syncthreads();
  if (threadIdx.x == 0) {
    float deg = (partial[0] + partial[1]) + (partial[2] + partial[3]) + 1.0f;
    dinv[row] = 1.0f / sqrtf(deg + 1e-8f);
  }
}

// ---- kernel 2: yT[f][i] = dinv[i] * x[i][f]  (bf16, transposed for NT GEMM) ----
__global__ __launch_bounds__(256) void k_scale_t(const float* __restrict__ x,
                                                 const float* __restrict__ dinv,
                                                 short* __restrict__ yT) {
  __shared__ float tile[64][129];
  const int r0 = blockIdx.x * 64;
  const int tid = threadIdx.x;
#pragma unroll
  for (int it = 0; it < 8; ++it) {
    int q = it * 256 + tid;     // float4 index in [0,2048)
    int r = q >> 5;             // 32 float4 per row
    int c = q & 31;
    float4 v = ((const float4*)(x + (size_t)(r0 + r) * FF))[c];
    float d = dinv[r0 + r];
    tile[r][c * 4 + 0] = v.x * d;
    tile[r][c * 4 + 1] = v.y * d;
    tile[r][c * 4 + 2] = v.z * d;
    tile[r][c * 4 + 3] = v.w * d;
  }
  __syncthreads();
  const int f = tid >> 1;
  const int i0 = (tid & 1) * 32;
#pragma unroll
  for (int g = 0; g < 4; ++g) {
    bf16x8 o;
#pragma unroll
    for (int j = 0; j < 8; ++j) o[j] = f2bf(tile[i0 + g * 8 + j][f]);
    *(bf16x8*)(yT + (size_t)f * NN + r0 + i0 + g * 8) = o;
  }
}

// ---- kernel 3: z = dinv * (adj @ y + y), bf16 MFMA, z -> d_out (scratch) ----
// BM=32, BN=128 (full F), BK=64. 512 threads = 8 waves, each wave a 32x16 strip.
__global__ __launch_bounds__(512) void k_gemm(const float* __restrict__ adj,
                                              const short* __restrict__ yT,
                                              const float* __restrict__ dinv,
                                              float* __restrict__ z) {
  __shared__ short As[32][72];    // +8 bf16 pad: breaks stride-128B bank conflict
  __shared__ short Bs[128][72];
  const int tid = threadIdx.x;
  const int wave = tid >> 6;
  const int lane = tid & 63;
  const int row0 = blockIdx.x * 32;

  // staging maps
  const int ar = tid >> 4;        // 0..31 (16 float4 per A row)
  const int ac4 = tid & 15;
  const int bcol = tid >> 3;      // 0..63 (8 x bf16x8 per B row), +64 in 2nd half
  const int bc8 = tid & 7;

  const float* aptr = adj + (size_t)(row0 + ar) * NN + ac4 * 4;
  const short* bptr0 = yT + (size_t)bcol * NN + bc8 * 8;
  const short* bptr1 = yT + (size_t)(bcol + 64) * NN + bc8 * 8;

  // prologue: load tile 0 into regs
  float4 aReg = *(const float4*)aptr;
  bf16x8 bReg0 = *(const bf16x8*)bptr0;
  bf16x8 bReg1 = *(const bf16x8*)bptr1;

  f32x4 acc0 = {0.f, 0.f, 0.f, 0.f};
  f32x4 acc1 = {0.f, 0.f, 0.f, 0.f};
  const int colbase = wave * 16;
  const int fr = lane & 15;
  const int kh = (lane >> 4) * 8;

  for (int k0 = 0; k0 < NN; k0 += 64) {
    // regs -> LDS (A converted to bf16 here)
    s16x4 ap;
    ap.x = f2bf(aReg.x); ap.y = f2bf(aReg.y); ap.z = f2bf(aReg.z); ap.w = f2bf(aReg.w);
    *(s16x4*)&As[ar][ac4 * 4] = ap;
    *(bf16x8*)&Bs[bcol][bc8 * 8] = bReg0;
    *(bf16x8*)&Bs[bcol + 64][bc8 * 8] = bReg1;
    __syncthreads();
    // prefetch next tile to regs; HBM latency hides under the MFMAs below
    if (k0 + 64 < NN) {
      aReg = *(const float4*)(aptr + k0 + 64);
      bReg0 = *(const bf16x8*)(bptr0 + k0 + 64);
      bReg1 = *(const bf16x8*)(bptr1 + k0 + 64);
    }
#pragma unroll
    for (int kk = 0; kk < 2; ++kk) {
      bf16x8 a0 = *(const bf16x8*)&As[fr][kk * 32 + kh];
      bf16x8 a1 = *(const bf16x8*)&As[16 + fr][kk * 32 + kh];
      bf16x8 b  = *(const bf16x8*)&Bs[colbase + fr][kk * 32 + kh];
      acc0 = __builtin_amdgcn_mfma_f32_16x16x32_bf16(a0, b, acc0, 0, 0, 0);
      acc1 = __builtin_amdgcn_mfma_f32_16x16x32_bf16(a1, b, acc1, 0, 0, 0);
    }
    __syncthreads();
  }

  // epilogue: + identity term, * dinv[row]; D layout: col=lane&15, row=(lane>>4)*4+r
  const int r4 = (lane >> 4) * 4;
  const int gf = colbase + fr;
#pragma unroll
  for (int m = 0; m < 2; ++m) {
#pragma unroll
    for (int r = 0; r < 4; ++r) {
      int gi = row0 + m * 16 + r4 + r;
      float acc = (m == 0) ? acc0[r] : acc1[r];
      float t = acc + bf2f(yT[(size_t)gf * NN + gi]);
      z[(size_t)gi * FF + gf] = dinv[gi] * t;
    }
  }
}

// ---- kernel 4: out = relu(z @ W), in place on d_out (z staged in LDS first) ----
__global__ __launch_bounds__(256) void k_wgemm(float* __restrict__ zo,
                                               const float* __restrict__ w) {
  __shared__ float zs[16][128];
  const int r0 = blockIdx.x * 16;
  const int tid = threadIdx.x;
#pragma unroll
  for (int it = 0; it < 2; ++it) {
    int q = it * 256 + tid;
    int r = q >> 5;
    int c = q & 31;
    float4 v = ((const float4*)(zo + (size_t)(r0 + r) * FF))[c];
    zs[r][c * 4 + 0] = v.x;
    zs[r][c * 4 + 1] = v.y;
    zs[r][c * 4 + 2] = v.z;
    zs[r][c * 4 + 3] = v.w;
  }
  __syncthreads();
  const int f = tid & 127;
  const int rg = (tid >> 7) * 8;
  float acc[8] = {0.f, 0.f, 0.f, 0.f, 0.f, 0.f, 0.f, 0.f};
#pragma unroll 4
  for (int k = 0; k < 128; ++k) {
    float wv = w[k * FF + f];
#pragma unroll
    for (int r = 0; r < 8; ++r) acc[r] += zs[rg + r][k] * wv;
  }
#pragma unroll
  for (int r = 0; r < 8; ++r) {
    zo[(size_t)(r0 + rg + r) * FF + f] = fmaxf(acc[r], 0.0f);
  }
}

extern "C" void kernel_launch(void* const* d_in, const int* in_sizes, int n_in,
                              void* d_out, int out_size, void* d_ws, size_t ws_size,
                              hipStream_t stream) {
  const float* x   = (const float*)d_in[0];
  const float* adj = (const float*)d_in[1];
  const float* w   = (const float*)d_in[2];
  float* out = (float*)d_out;

  float* dinv = (float*)d_ws;                                // 32 KiB
  short* yT   = (short*)((char*)d_ws + 8192 * sizeof(float)); // 2 MiB bf16 [128][8192]

  k_deg    <<<NN,      256, 0, stream>>>(adj, dinv);
  k_scale_t<<<NN / 64, 256, 0, stream>>>(x, dinv, yT);
  k_gemm   <<<NN / 32, 512, 0, stream>>>(adj, yT, dinv, out);
  k_wgemm  <<<NN / 16, 256, 0, stream>>>(out, w);
}